// Round 1
// baseline (720.069 us; speedup 1.0000x reference)
//
#include <hip/hip_runtime.h>

#define B_ 16
#define H_ 12
#define N_ 784
#define NN_ (N_ * N_)      // 614656
#define NF4_ (N_ / 4)      // 196 float4 per row
#define BPB_ 128           // blocks per batch for softmax passes

// ---- init: zero per-batch max bits and sums (ws is poisoned 0xAA) ----
__global__ void init_kernel(int* __restrict__ maxbits, float* __restrict__ sums) {
    int t = threadIdx.x;
    if (t < B_) { maxbits[t] = 0; sums[t] = 0.0f; }
}

// ---- pass 1: fused rowsum + head-weighted aggregate + per-batch max ----
// One wave per (b,i) row. Each lane holds up to 4 float4 of the current head
// row in registers; rowsum via wave shuffle-reduce; accumulate agg in regs.
__global__ __launch_bounds__(256) void agg_kernel(
    const float* __restrict__ m, float* __restrict__ agg,
    int* __restrict__ maxbits) {
    const int lane = threadIdx.x & 63;
    const int wave = threadIdx.x >> 6;
    const int row  = blockIdx.x * 4 + wave;   // row index in [0, B*N)
    const int b = row / N_;
    const int i = row - b * N_;

    float4 acc[4];
#pragma unroll
    for (int k = 0; k < 4; ++k) acc[k] = make_float4(0.f, 0.f, 0.f, 0.f);

#pragma unroll
    for (int h = 0; h < H_; ++h) {
        const float4* p =
            (const float4*)m + ((size_t)(b * H_ + h) * N_ + i) * NF4_;
        float4 r[4];
        float s = 0.f;
#pragma unroll
        for (int k = 0; k < 4; ++k) {
            int idx = k * 64 + lane;
            if (idx < NF4_) {
                r[k] = p[idx];
                s += r[k].x + r[k].y + r[k].z + r[k].w;
            } else {
                r[k] = make_float4(0.f, 0.f, 0.f, 0.f);
            }
        }
        // wave-wide sum -> every lane has the row sum
#pragma unroll
        for (int off = 32; off > 0; off >>= 1) s += __shfl_xor(s, off, 64);
#pragma unroll
        for (int k = 0; k < 4; ++k) {
            acc[k].x += r[k].x * s;
            acc[k].y += r[k].y * s;
            acc[k].z += r[k].z * s;
            acc[k].w += r[k].w * s;
        }
    }

    float4* outp = (float4*)agg + ((size_t)b * N_ + i) * NF4_;
    float mx = 0.f;  // values are >= 0
#pragma unroll
    for (int k = 0; k < 4; ++k) {
        int idx = k * 64 + lane;
        if (idx < NF4_) {
            outp[idx] = acc[k];
            mx = fmaxf(mx, fmaxf(fmaxf(acc[k].x, acc[k].y),
                                 fmaxf(acc[k].z, acc[k].w)));
        }
    }
#pragma unroll
    for (int off = 32; off > 0; off >>= 1)
        mx = fmaxf(mx, __shfl_xor(mx, off, 64));
    if (lane == 0) atomicMax(&maxbits[b], __float_as_int(mx));
}

// ---- pass 2: in-place exp(x - max_b) and per-batch sum ----
__global__ __launch_bounds__(256) void expsum_kernel(
    float* __restrict__ agg, const int* __restrict__ maxbits,
    float* __restrict__ sums) {
    const int b   = blockIdx.x / BPB_;
    const int blk = blockIdx.x % BPB_;
    const float mx = __int_as_float(maxbits[b]);
    float4* p = (float4*)agg + (size_t)b * (NN_ / 4);
    float s = 0.f;
    for (int idx = blk * 256 + threadIdx.x; idx < NN_ / 4; idx += BPB_ * 256) {
        float4 v = p[idx];
        v.x = __expf(v.x - mx);
        v.y = __expf(v.y - mx);
        v.z = __expf(v.z - mx);
        v.w = __expf(v.w - mx);
        p[idx] = v;
        s += v.x + v.y + v.z + v.w;
    }
#pragma unroll
    for (int off = 32; off > 0; off >>= 1) s += __shfl_xor(s, off, 64);
    __shared__ float red[4];
    if ((threadIdx.x & 63) == 0) red[threadIdx.x >> 6] = s;
    __syncthreads();
    if (threadIdx.x == 0)
        atomicAdd(&sums[b], red[0] + red[1] + red[2] + red[3]);
}

// ---- pass 3: scale by 1/sum_b ----
__global__ __launch_bounds__(256) void scale_kernel(
    float* __restrict__ agg, const float* __restrict__ sums) {
    const int b   = blockIdx.x / BPB_;
    const int blk = blockIdx.x % BPB_;
    const float inv = 1.0f / sums[b];
    float4* p = (float4*)agg + (size_t)b * (NN_ / 4);
    for (int idx = blk * 256 + threadIdx.x; idx < NN_ / 4; idx += BPB_ * 256) {
        float4 v = p[idx];
        v.x *= inv; v.y *= inv; v.z *= inv; v.w *= inv;
        p[idx] = v;
    }
}

extern "C" void kernel_launch(void* const* d_in, const int* in_sizes, int n_in,
                              void* d_out, int out_size, void* d_ws,
                              size_t ws_size, hipStream_t stream) {
    const float* m = (const float*)d_in[0];
    float* out = (float*)d_out;            // doubles as agg scratch
    int*   maxbits = (int*)d_ws;
    float* sums    = (float*)((char*)d_ws + B_ * sizeof(int));

    hipLaunchKernelGGL(init_kernel, dim3(1), dim3(64), 0, stream,
                       maxbits, sums);
    hipLaunchKernelGGL(agg_kernel, dim3(B_ * N_ / 4), dim3(256), 0, stream,
                       m, out, maxbits);
    hipLaunchKernelGGL(expsum_kernel, dim3(B_ * BPB_), dim3(256), 0, stream,
                       out, maxbits, sums);
    hipLaunchKernelGGL(scale_kernel, dim3(B_ * BPB_), dim3(256), 0, stream,
                       out, sums);
}